// Round 1
// baseline (274.892 us; speedup 1.0000x reference)
//
#include <hip/hip_runtime.h>

#define NROWS 131072
#define DIMS  64
#define KC    1024
#define BETA  0.25f

// output offsets (floats)
#define OFF_Q      0
#define OFF_LOSS   8388608
#define OFF_EMB    8388609
#define OFF_COUNT  (8388609 + 65536)
#define OFF_EMBSUM (8388609 + 65536 + 1024)

// ws layout (floats)
#define WS_LOSS   0
#define WS_COUNTS 64
#define WS_SUMS   (64 + 1024)                 // [K][D]
#define WS_NORME  (64 + 1024 + 65536)
#define WS_TOTAL  (64 + 1024 + 65536 + 1024)

constexpr int BM = 64;   // rows per block
constexpr int BN = 64;   // codes per LDS chunk
constexpr int NT = 256;

__global__ void norme_kernel(const float* __restrict__ emb, float* __restrict__ ws) {
    int k = blockIdx.x * blockDim.x + threadIdx.x;
    if (k < KC) {
        float s = 0.f;
        #pragma unroll 8
        for (int d = 0; d < DIMS; ++d) {
            float v = emb[(size_t)d * KC + k];
            s += v * v;
        }
        ws[WS_NORME + k] = s;
    }
}

__launch_bounds__(NT)
__global__ void vq_main(const float* __restrict__ x, const float* __restrict__ emb,
                        float* __restrict__ q_out, float* __restrict__ ws) {
    __shared__ float xT[DIMS][BM];     // [d][r]
    __shared__ float eL[DIMS][BN];     // [d][kk]
    __shared__ float red_d[16][BM];
    __shared__ int   red_k[16][BM];
    __shared__ int   best_k[BM];

    const int t = threadIdx.x;
    const int row0 = blockIdx.x * BM;

    // stage x tile transposed
    for (int i = t; i < BM * (DIMS / 4); i += NT) {   // 1024 float4 ids
        int r  = i >> 4;
        int dc = (i & 15) << 2;
        float4 v = *reinterpret_cast<const float4*>(x + (size_t)(row0 + r) * DIMS + dc);
        xT[dc + 0][r] = v.x; xT[dc + 1][r] = v.y;
        xT[dc + 2][r] = v.z; xT[dc + 3][r] = v.w;
    }

    const int tx = t & 15;
    const int ty = t >> 4;
    const int rb = ty * 4;
    const int kb = tx * 4;

    float bdist[4] = {1e30f, 1e30f, 1e30f, 1e30f};
    int   bidx [4] = {0, 0, 0, 0};

    for (int kc0 = 0; kc0 < KC; kc0 += BN) {
        __syncthreads();   // protects eL from prev iter readers (and xT on first iter)
        for (int i = t; i < DIMS * (BN / 4); i += NT) {
            int d  = i >> 4;
            int kk = (i & 15) << 2;
            *reinterpret_cast<float4*>(&eL[d][kk]) =
                *reinterpret_cast<const float4*>(emb + (size_t)d * KC + kc0 + kk);
        }
        __syncthreads();

        float acc[4][4] = {};
        #pragma unroll 8
        for (int d = 0; d < DIMS; ++d) {
            float4 a = *reinterpret_cast<const float4*>(&xT[d][rb]);
            float4 b = *reinterpret_cast<const float4*>(&eL[d][kb]);
            acc[0][0] += a.x * b.x; acc[0][1] += a.x * b.y; acc[0][2] += a.x * b.z; acc[0][3] += a.x * b.w;
            acc[1][0] += a.y * b.x; acc[1][1] += a.y * b.y; acc[1][2] += a.y * b.z; acc[1][3] += a.y * b.w;
            acc[2][0] += a.z * b.x; acc[2][1] += a.z * b.y; acc[2][2] += a.z * b.z; acc[2][3] += a.z * b.w;
            acc[3][0] += a.w * b.x; acc[3][1] += a.w * b.y; acc[3][2] += a.w * b.z; acc[3][3] += a.w * b.w;
        }

        #pragma unroll
        for (int c = 0; c < 4; ++c) {
            int k = kc0 + kb + c;
            float nE = ws[WS_NORME + k];
            #pragma unroll
            for (int r = 0; r < 4; ++r) {
                float dist = nE - 2.f * acc[r][c];
                if (dist < bdist[r]) { bdist[r] = dist; bidx[r] = k; }
            }
        }
    }

    #pragma unroll
    for (int r = 0; r < 4; ++r) {
        red_d[tx][rb + r] = bdist[r];
        red_k[tx][rb + r] = bidx[r];
    }
    __syncthreads();

    if (t < BM) {
        float bd = red_d[0][t]; int bk = red_k[0][t];
        #pragma unroll
        for (int j = 1; j < 16; ++j) {
            float dj = red_d[j][t]; int kj = red_k[j][t];
            if (dj < bd || (dj == bd && kj < bk)) { bd = dj; bk = kj; }
        }
        best_k[t] = bk;
        atomicAdd(&ws[WS_COUNTS + bk], 1.0f);
    }
    __syncthreads();

    // quantized write + loss + scatter sums
    float lsum = 0.f;
    for (int it = 0; it < 16; ++it) {
        int r = it * 4 + (t >> 6);
        int d = t & 63;
        int k = best_k[r];
        float q = emb[(size_t)d * KC + k];
        size_t gi = (size_t)(row0 + r) * DIMS + d;
        float xv = x[gi];
        float diff = q - xv;
        lsum += diff * diff;
        q_out[gi] = q;
        atomicAdd(&ws[WS_SUMS + k * DIMS + d], xv);
    }

    #pragma unroll
    for (int o = 32; o > 0; o >>= 1) lsum += __shfl_down(lsum, o);
    if ((t & 63) == 0) atomicAdd(&ws[WS_LOSS], lsum);
}

__global__ void vq_final(const float* __restrict__ sample_count,
                         const float* __restrict__ embeddings_sum,
                         const float* __restrict__ ws, float* __restrict__ out) {
    int i = blockIdx.x * blockDim.x + threadIdx.x;   // over D*K
    int d = i >> 10;
    int k = i & 1023;
    float cnt = sample_count[k] + ws[WS_COUNTS + k];
    float ns  = embeddings_sum[i] + ws[WS_SUMS + k * DIMS + d];
    out[OFF_EMBSUM + i] = ns;
    out[OFF_EMB + i]    = ns / fmaxf(cnt, 1e-5f);
    if (i < KC) out[OFF_COUNT + i] = sample_count[i] + ws[WS_COUNTS + i];
    if (i == 0) out[OFF_LOSS] = BETA * ws[WS_LOSS] * (1.0f / ((float)NROWS * (float)DIMS));
}

extern "C" void kernel_launch(void* const* d_in, const int* in_sizes, int n_in,
                              void* d_out, int out_size, void* d_ws, size_t ws_size,
                              hipStream_t stream) {
    const float* x      = (const float*)d_in[0];
    const float* emb    = (const float*)d_in[1];
    const float* scount = (const float*)d_in[2];
    const float* esum   = (const float*)d_in[3];
    float* out = (float*)d_out;
    float* ws  = (float*)d_ws;

    hipMemsetAsync(d_ws, 0, WS_TOTAL * sizeof(float), stream);
    norme_kernel<<<KC / NT, NT, 0, stream>>>(emb, ws);
    vq_main<<<NROWS / BM, NT, 0, stream>>>(x, emb, out, ws);
    vq_final<<<(DIMS * KC) / NT, NT, 0, stream>>>(scount, esum, ws, out);
}

// Round 2
// 180.903 us; speedup vs baseline: 1.5196x; 1.5196x over previous
//
#include <hip/hip_runtime.h>

typedef _Float16 f16;
typedef _Float16 f16x8 __attribute__((ext_vector_type(8)));
typedef float f32x4 __attribute__((ext_vector_type(4)));

#define NROWS 131072
#define DIMS  64
#define KC    1024
#define BETA  0.25f

// output offsets (floats)
#define OFF_Q      0
#define OFF_LOSS   8388608
#define OFF_EMB    8388609
#define OFF_COUNT  (8388609 + 65536)
#define OFF_EMBSUM (8388609 + 65536 + 1024)

// ws layout (floats)
#define WS_LOSS   0
#define WS_COUNTS 64
#define WS_SUMS   (64 + 1024)                 // [K][D]
#define WS_NORME  (64 + 1024 + 65536)
#define WS_TOTAL  (64 + 1024 + 65536 + 1024)

// Prep: transpose emb [D][K] -> f16 hi/lo [K][D] (stashed in d_out's EMBSUM
// region, overwritten later by vq_final), plus normE[k] = sum_d e^2 in fp32.
__global__ void vq_prep(const float* __restrict__ emb, float* __restrict__ ws,
                        f16* __restrict__ ehT, f16* __restrict__ elT) {
    __shared__ float buf[64][65];
    const int t = threadIdx.x;
    const int k0 = blockIdx.x * 64;
    #pragma unroll
    for (int it = 0; it < 16; ++it) {
        int idx = it * 256 + t;
        int kk = idx & 63, d = idx >> 6;
        buf[kk][d] = emb[(size_t)d * KC + k0 + kk];   // coalesced over kk
    }
    __syncthreads();
    if (t < 64) {
        float s = 0.f;
        #pragma unroll 8
        for (int d = 0; d < 64; ++d) { float v = buf[t][d]; s += v * v; }
        ws[WS_NORME + k0 + t] = s;
    }
    #pragma unroll
    for (int it = 0; it < 16; ++it) {
        int idx = it * 256 + t;
        int d = idx & 63, kk = idx >> 6;
        float v = buf[kk][d];
        f16 hi = (f16)v;
        f16 lo = (f16)(v - (float)hi);
        ehT[(size_t)(k0 + kk) * 64 + d] = hi;         // coalesced over d
        elT[(size_t)(k0 + kk) * 64 + d] = lo;
    }
}

__launch_bounds__(256)
__global__ void vq_main(const float* __restrict__ x, const f16* __restrict__ ehT,
                        const f16* __restrict__ elT, float* __restrict__ q_out,
                        float* __restrict__ ws) {
    __shared__ f16 eh[128 * 64];     // XOR-swizzled [code][d]
    __shared__ f16 el[128 * 64];
    __shared__ int best_k[128];

    const int t    = threadIdx.x;
    const int lane = t & 63;
    const int wv   = t >> 6;         // 4 waves, 32 rows each
    const int brow = blockIdx.x * 128;
    const int l15  = lane & 15;
    const int l4   = lane >> 4;

    // A fragments: rows of x converted to f16 hi/lo in registers.
    // mfma_f32_16x16x32_f16 A layout: row = lane&15, k = (lane>>4)*8 + j
    f16x8 ahi[2][2], alo[2][2];
    #pragma unroll
    for (int rt = 0; rt < 2; ++rt) {
        int row = brow + wv * 32 + rt * 16 + l15;
        #pragma unroll
        for (int ks = 0; ks < 2; ++ks) {
            int d0 = ks * 32 + l4 * 8;
            const float* p = x + (size_t)row * 64 + d0;
            float4 v0 = *(const float4*)p;
            float4 v1 = *(const float4*)(p + 4);
            float vv[8] = {v0.x, v0.y, v0.z, v0.w, v1.x, v1.y, v1.z, v1.w};
            f16x8 h, l;
            #pragma unroll
            for (int j = 0; j < 8; ++j) {
                f16 hj = (f16)vv[j];
                h[j] = hj;
                l[j] = (f16)(vv[j] - (float)hj);
            }
            ahi[rt][ks] = h; alo[rt][ks] = l;
        }
    }

    float bdist[2][4];
    int   bidx[2][4];
    #pragma unroll
    for (int rt = 0; rt < 2; ++rt)
        #pragma unroll
        for (int r = 0; r < 4; ++r) { bdist[rt][r] = 1e30f; bidx[rt][r] = 0; }

    const char* ehTb = (const char*)ehT;
    const char* elTb = (const char*)elT;
    char* ehb = (char*)eh;
    char* elb = (char*)el;

    for (int kc0 = 0; kc0 < KC; kc0 += 128) {
        __syncthreads();
        // stage 128 codes x 64 dims, hi+lo (16KB each); XOR-swizzle dest so
        // B-frag ds_read_b128 (row stride 128B) is bank-conflict-free.
        #pragma unroll
        for (int it = 0; it < 4; ++it) {
            int n = (it * 256 + t) * 16;          // byte offset within chunk
            int code  = n >> 7;
            int inner = n & 127;
            int dswz  = (code << 7) | (inner ^ ((code & 7) << 4));
            float4 vh = *(const float4*)(ehTb + (size_t)kc0 * 128 + n);
            float4 vl = *(const float4*)(elTb + (size_t)kc0 * 128 + n);
            *(float4*)(ehb + dswz) = vh;
            *(float4*)(elb + dswz) = vl;
        }
        __syncthreads();

        #pragma unroll
        for (int ct = 0; ct < 8; ++ct) {
            int code = ct * 16 + l15;             // B col = lane&15
            f16x8 bh[2], bl[2];
            #pragma unroll
            for (int ks = 0; ks < 2; ++ks) {
                int inner = ks * 64 + l4 * 16;    // k = (lane>>4)*8 + j
                int off = (code << 7) | (inner ^ ((code & 7) << 4));
                bh[ks] = *(const f16x8*)(ehb + off);
                bl[ks] = *(const f16x8*)(elb + off);
            }
            int gcol = kc0 + code;
            float nE = ws[WS_NORME + gcol];
            #pragma unroll
            for (int rt = 0; rt < 2; ++rt) {
                f32x4 acc = {0.f, 0.f, 0.f, 0.f};
                #pragma unroll
                for (int ks = 0; ks < 2; ++ks) {
                    acc = __builtin_amdgcn_mfma_f32_16x16x32_f16(ahi[rt][ks], bh[ks], acc, 0, 0, 0);
                    acc = __builtin_amdgcn_mfma_f32_16x16x32_f16(alo[rt][ks], bh[ks], acc, 0, 0, 0);
                    acc = __builtin_amdgcn_mfma_f32_16x16x32_f16(ahi[rt][ks], bl[ks], acc, 0, 0, 0);
                }
                // C/D layout: col = lane&15, row = (lane>>4)*4 + reg
                #pragma unroll
                for (int r = 0; r < 4; ++r) {
                    float dist = nE - 2.f * acc[r];
                    if (dist < bdist[rt][r]) { bdist[rt][r] = dist; bidx[rt][r] = gcol; }
                }
            }
        }
    }

    // reduce argmin across the 16 lanes holding the same row (vary lane&15)
    #pragma unroll
    for (int rt = 0; rt < 2; ++rt) {
        #pragma unroll
        for (int r = 0; r < 4; ++r) {
            float d = bdist[rt][r]; int k = bidx[rt][r];
            #pragma unroll
            for (int m = 1; m <= 8; m <<= 1) {
                float d2 = __shfl_xor(d, m, 64);
                int   k2 = __shfl_xor(k, m, 64);
                if (d2 < d || (d2 == d && k2 < k)) { d = d2; k = k2; }
            }
            if (l15 == 0) {
                int rloc = wv * 32 + rt * 16 + l4 * 4 + r;
                best_k[rloc] = k;
                atomicAdd(&ws[WS_COUNTS + k], 1.0f);
            }
        }
    }
    __syncthreads();

    // epilogue: quantized gather (exact e = hi+lo), loss, scatter sums
    float lsum = 0.f;
    for (int it = 0; it < 32; ++it) {
        int r = it * 4 + wv;
        int d = lane;
        int k = best_k[r];                        // wave-uniform broadcast
        float q = (float)ehT[(size_t)k * 64 + d] + (float)elT[(size_t)k * 64 + d];
        size_t gi = (size_t)(brow + r) * 64 + d;
        float xv = x[gi];
        float diff = q - xv;
        lsum += diff * diff;
        q_out[gi] = q;
        atomicAdd(&ws[WS_SUMS + k * 64 + d], xv);
    }
    #pragma unroll
    for (int o = 32; o > 0; o >>= 1) lsum += __shfl_down(lsum, o);
    if (lane == 0) atomicAdd(&ws[WS_LOSS], lsum);
}

__global__ void vq_final(const float* __restrict__ sample_count,
                         const float* __restrict__ embeddings_sum,
                         const float* __restrict__ ws, float* __restrict__ out) {
    int i = blockIdx.x * blockDim.x + threadIdx.x;   // over D*K
    int d = i >> 10;
    int k = i & 1023;
    float cnt = sample_count[k] + ws[WS_COUNTS + k];
    float ns  = embeddings_sum[i] + ws[WS_SUMS + k * DIMS + d];
    out[OFF_EMBSUM + i] = ns;
    out[OFF_EMB + i]    = ns / fmaxf(cnt, 1e-5f);
    if (i < KC) out[OFF_COUNT + i] = sample_count[i] + ws[WS_COUNTS + i];
    if (i == 0) out[OFF_LOSS] = BETA * ws[WS_LOSS] * (1.0f / ((float)NROWS * (float)DIMS));
}

extern "C" void kernel_launch(void* const* d_in, const int* in_sizes, int n_in,
                              void* d_out, int out_size, void* d_ws, size_t ws_size,
                              hipStream_t stream) {
    const float* x      = (const float*)d_in[0];
    const float* emb    = (const float*)d_in[1];
    const float* scount = (const float*)d_in[2];
    const float* esum   = (const float*)d_in[3];
    float* out = (float*)d_out;
    float* ws  = (float*)d_ws;

    // f16 hi/lo transposed codebook lives in the EMBSUM output region until
    // vq_final overwrites it (131072B + 131072B == 65536 floats exactly).
    f16* ehT = (f16*)(out + OFF_EMBSUM);
    f16* elT = ehT + KC * DIMS;

    hipMemsetAsync(d_ws, 0, WS_TOTAL * sizeof(float), stream);
    vq_prep<<<KC / 64, 256, 0, stream>>>(emb, ws, ehT, elT);
    vq_main<<<NROWS / 128, 256, 0, stream>>>(x, ehT, elT, out, ws);
    vq_final<<<(DIMS * KC) / 256, 256, 0, stream>>>(scount, esum, ws, out);
}